// Round 10
// baseline (308.010 us; speedup 1.0000x reference)
//
#include <hip/hip_runtime.h>
#include <hip/hip_bf16.h>
#include <math.h>

typedef __bf16 bf16;
typedef __bf16 bf16x8 __attribute__((ext_vector_type(8)));
typedef __bf16 bf16x4 __attribute__((ext_vector_type(4)));
typedef float f32x4 __attribute__((ext_vector_type(4)));

#define MFMA16(a, b, c) __builtin_amdgcn_mfma_f32_16x16x32_bf16((a), (b), (c), 0, 0, 0)
#define EXP2F(x) __builtin_amdgcn_exp2f(x)  // v_exp_f32: computes 2^x

// async global->LDS, 16B per lane; LDS dest = (wave-uniform) base + lane*16
__device__ __forceinline__ void gl_lds16(const bf16* g, bf16* l) {
  __builtin_amdgcn_global_load_lds(
      (const __attribute__((address_space(1))) void*)g,
      (__attribute__((address_space(3))) void*)l, 16, 0, 0);
}

// problem dims
static constexpr int B_N = 2, S_N = 2048, DM = 1024, H_N = 16, DK = 64;
static constexpr int M_N = B_N * S_N;             // 4096
static constexpr size_t NX = (size_t)M_N * DM;    // 4M elements
static constexpr size_t NW = (size_t)DM * DM;     // 1M elements
// workspace layout (bf16 elements)
static constexpr size_t OFF_X = 0;
static constexpr size_t OFF_W = NX;               // Wq,Wk,Wv,Wo
static constexpr size_t OFF_Q = OFF_W + 4 * NW;   // Q [b,h,s,d] (pre-scaled by log2e/8, roped)
static constexpr size_t OFF_K = OFF_Q + NX;       // K [b,h,s,d] (roped)
static constexpr size_t OFF_V = OFF_K + NX;       // V^T [b,h,d,s]
static constexpr size_t OFF_C = OFF_V + NX;       // ctx [b,s,h*d]; rope table aliases its head
// total 24M bf16 = 48 MB

// ---------------- fp32 -> bf16 cast + RoPE table (fused) ----------------
__global__ __launch_bounds__(256) void cast_all(
    const float* __restrict__ x, const float* __restrict__ wq,
    const float* __restrict__ wk, const float* __restrict__ wv,
    const float* __restrict__ wo, bf16* __restrict__ dst,
    float2* __restrict__ tab) {
  size_t i = ((size_t)blockIdx.x * 256 + threadIdx.x) * 4;
  const float* src;
  size_t off;
  if (i < NX) {
    src = x; off = i;
  } else {
    size_t e = i - NX;
    int wi = (int)(e >> 20);
    src = (wi == 0) ? wq : (wi == 1) ? wk : (wi == 2) ? wv : wo;
    off = e & (NW - 1);
  }
  float4 v = *(const float4*)(src + off);
  bf16x4 o = {(bf16)v.x, (bf16)v.y, (bf16)v.z, (bf16)v.w};
  *(bf16x4*)(dst + i) = o;
  if (blockIdx.x < 256) {
    int t = blockIdx.x * 256 + threadIdx.x;  // 65536 entries
    int s = t >> 5, j = t & 31;
    float invf = powf(10000.f, -(float)(2 * j) / 64.f);
    float sn, cs;
    sincosf((float)s * invf, &sn, &cs);
    tab[t] = make_float2(cs, sn);
  }
}

// ---------------- QKV GEMM (M=4096,N=3072,K=1024) + fused RoPE, V written transposed ----------------
__global__ __launch_bounds__(256) void gemm_qkv_rope(
    const bf16* __restrict__ X, const bf16* __restrict__ W3,
    const int* __restrict__ pos_ids, const float2* __restrict__ tab,
    bf16* __restrict__ Qo, bf16* __restrict__ Ko, bf16* __restrict__ Vt) {
  __shared__ __align__(16) bf16 As[128 * 32];
  __shared__ __align__(16) bf16 Bs[128 * 32];
  const int tid = threadIdx.x;
  const int wave = tid >> 6, lane = tid & 63;
  const int c15 = lane & 15, g = lane >> 4;
  const int mw = (wave & 1) * 64, nw = (wave >> 1) * 64;
  const int row0 = blockIdx.x * 128;
  const int n0 = blockIdx.y * 128;
  const bf16* Asrc = X + (size_t)row0 * DM;
  const bf16* Bsrc = W3 + (size_t)n0 * DM;
  const int srA = wave * 32 + (lane >> 2);
  const int cph = lane & 3;

  f32x4 acc[4][4] = {};
  for (int kt = 0; kt < DM / 32; ++kt) {
    const int k0 = kt * 32;
    __syncthreads();
#pragma unroll
    for (int c = 0; c < 2; ++c) {
      const int r = srA + c * 16;
      gl_lds16(Asrc + (size_t)r * DM + k0 + cph * 8, &As[wave * 1024 + c * 512]);
      gl_lds16(Bsrc + (size_t)r * DM + k0 + cph * 8, &Bs[wave * 1024 + c * 512]);
    }
    __syncthreads();
    bf16x8 af[4], bfr[4];
#pragma unroll
    for (int t = 0; t < 4; ++t)
      af[t] = *(const bf16x8*)&As[(mw + t * 16 + c15) * 32 + g * 8];
#pragma unroll
    for (int t = 0; t < 4; ++t)
      bfr[t] = *(const bf16x8*)&Bs[(nw + t * 16 + c15) * 32 + g * 8];
#pragma unroll
    for (int mt = 0; mt < 4; ++mt)
#pragma unroll
      for (int nt = 0; nt < 4; ++nt)
        acc[mt][nt] = MFMA16(af[mt], bfr[nt], acc[mt][nt]);
  }

  // epilogue: C/D col = nt*16+c15, row = g*4+r
  const int Wsel = n0 >> 10;             // 0=q, 1=k, 2=v
  const int colbase = (n0 & 1023) + nw;  // multiple of 64 -> one head
  const int h = colbase >> 6;
  if (Wsel == 2) {
#pragma unroll
    for (int mt = 0; mt < 4; ++mt) {
      const int srow = row0 + mw + mt * 16 + g * 4;
      const int bb = srow >> 11, ss = srow & 2047;
      const size_t vb = ((size_t)(bb * H_N + h) * DK) * S_N + ss;
#pragma unroll
      for (int nt = 0; nt < 4; ++nt) {
        bf16x4 v4;
#pragma unroll
        for (int r = 0; r < 4; ++r) v4[r] = (bf16)acc[mt][nt][r];
        *(bf16x4*)&Vt[vb + (size_t)(nt * 16 + c15) * S_N] = v4;
      }
    }
  } else {
    bf16* dst = (Wsel == 0) ? Qo : Ko;
    // Q pre-scale folds 1/sqrt(64) AND log2(e) so flash can use exp2 directly.
    const float sc = (Wsel == 0) ? 0.125f * 1.44269504088896f : 1.0f;
#pragma unroll
    for (int mt = 0; mt < 4; ++mt) {
#pragma unroll
      for (int r = 0; r < 4; ++r) {
        const int row = row0 + mw + mt * 16 + g * 4 + r;
        const int bb = row >> 11, ss = row & 2047;
        const int pos = pos_ids[row];
        const float2 c0 = tab[pos * 32 + c15];       // freq j = c15
        const float2 c1 = tab[pos * 32 + 16 + c15];  // freq j = 16+c15
        const size_t base = ((size_t)(bb * H_N + h) * S_N + ss) * DK;
#pragma unroll
        for (int ntp = 0; ntp < 2; ++ntp) {
          float x1 = acc[mt][ntp][r], x2 = acc[mt][ntp + 2][r];
          float cs = ntp ? c1.x : c0.x, sn = ntp ? c1.y : c0.y;
          dst[base + ntp * 16 + c15] = (bf16)((x1 * cs - x2 * sn) * sc);
          dst[base + ntp * 16 + c15 + 32] = (bf16)((x2 * cs + x1 * sn) * sc);
        }
      }
    }
  }
}

// ---------------- flash attention: split-key waves, SHARED staging, 4 blocks/CU ----------------
// 128 q/block, 4 waves = (qh: 64-q half) x (ky: 32-key slice). K/V tiles shared per
// ky-pair: qh=0 wave stages K, qh=1 stages V (16 gl_lds/block-iter vs 32 in R9).
// One __syncthreads per iter + dbuf (R7 pattern). O,l additive over ky -> one merge.
__global__ __launch_bounds__(256, 4) void flash_attn(
    const bf16* __restrict__ Q, const bf16* __restrict__ K,
    const bf16* __restrict__ Vt, bf16* __restrict__ ctx) {
  // carve one contiguous block: K[ky][buf] | V[ky][buf] | P[wave]  (elements)
  //   K: [0, 8192)   slice(ky,buf) at (ky*2+buf)*2048
  //   V: [8192, 16384)
  //   P: [16384, 18944)  wave*640, rows 16 stride 40
  __shared__ __align__(16) bf16 smem[18944];
  __shared__ float lred[2][4][16];
  float* redbuf = (float*)smem;  // merge scratch: 2 qh x 64 rows x stride 68 floats

  const int tid = threadIdx.x;
  const int wave = tid >> 6, lane = tid & 63;
  const int c15 = lane & 15, g = lane >> 4;
  const int qh = wave >> 1, ky = wave & 1;
  const int bh = blockIdx.x & 31;   // b*16+h (XCD = bh%8)
  const int qt = blockIdx.x >> 5;   // 128-query tile, 0..15
  const size_t hb = (size_t)bh * S_N * DK;
  const bf16* Qb = Q + hb;
  const bf16* Kb = K + hb;
  const bf16* Vb = Vt + hb;  // [d][s] rows, stride S_N
  bf16* Pw = &smem[16384 + wave * 640];

  // Q B-frags: 4 q-tiles of 16 for this wave's 64-query half
  const int qb = qt * 128 + qh * 64;
  bf16x8 qf[4][2];
#pragma unroll
  for (int t = 0; t < 4; ++t) {
    qf[t][0] = *(const bf16x8*)&Qb[(size_t)(qb + t * 16 + c15) * DK + g * 8];
    qf[t][1] = *(const bf16x8*)&Qb[(size_t)(qb + t * 16 + c15) * DK + 32 + g * 8];
  }

  f32x4 O[4][4] = {};  // [q-tile][d-tile]: O^T row d = nt*16+g*4+r, col q = c15
  float l[4] = {0.f, 0.f, 0.f, 0.f};
  const int sw = c15 & 7;
  const int vslot = (g + (c15 >> 1)) & 3;  // V read-granule swizzle

  constexpr int NTK = S_N / 64;  // 32 iters; each wave sees its ky 32-key slice
#define STAGE(kt_, b_)                                                            \
  if (qh == 0) { /* stage K slice ky */                                           \
    const bf16* Ksrc = Kb + (size_t)((kt_)*64 + ky * 32) * DK;                    \
    _Pragma("unroll") for (int c = 0; c < 4; ++c) {                               \
      const int gi = c * 64 + lane;                                               \
      const int rr = gi >> 3, cp = gi & 7;                                        \
      const int cd = cp ^ (rr & 7);                                               \
      gl_lds16(Ksrc + (size_t)rr * 64 + cd * 8, &smem[(ky * 2 + (b_)) * 2048 + c * 512]); \
    }                                                                             \
  } else { /* stage V slice ky */                                                 \
    const bf16* Vsrc = Vb + (kt_)*64 + ky * 32;                                   \
    _Pragma("unroll") for (int c = 0; c < 4; ++c) {                               \
      const int gi = c * 64 + lane;                                               \
      const int rv = gi >> 2, cpv = gi & 3;                                       \
      const int cdv = (cpv - ((rv & 15) >> 1)) & 3;                               \
      gl_lds16(Vsrc + (size_t)rv * S_N + cdv * 8, &smem[8192 + (ky * 2 + (b_)) * 2048 + c * 512]); \
    }                                                                             \
  }

  STAGE(0, 0)
  for (int kt = 0; kt < NTK; ++kt) {
    __syncthreads();  // tile kt resident (its loads were issued one full phase ago)
    if (kt + 1 < NTK) STAGE(kt + 1, (kt + 1) & 1)
    const bf16* Kl = &smem[(ky * 2 + (kt & 1)) * 2048];
    const bf16* Vl = &smem[8192 + (ky * 2 + (kt & 1)) * 2048];

    // K A-frags: 2 key-subtiles x 2 d-halves (granule-XOR swizzle, round-trips cd)
    bf16x8 kf[2][2];
#pragma unroll
    for (int nt = 0; nt < 2; ++nt) {
      const int krow = (nt * 16 + c15) * 64;
      kf[nt][0] = *(const bf16x8*)&Kl[krow + ((g ^ sw) * 8)];
      kf[nt][1] = *(const bf16x8*)&Kl[krow + (((4 | g) ^ sw) * 8)];
    }
    // V A-frags: 4 d-subtiles, k = 32 keys (slot swizzle: data granule g at vslot)
    bf16x8 vf[4];
#pragma unroll
    for (int nt = 0; nt < 4; ++nt)
      vf[nt] = *(const bf16x8*)&Vl[(nt * 16 + c15) * 32 + vslot * 8];

    // per q-tile: S^T = K·Q^T (32 keys x 16 q) -> exp2 -> P LDS -> PV
#pragma unroll
    for (int t = 0; t < 4; ++t) {
      f32x4 s0 = {}, s1 = {};
      s0 = MFMA16(kf[0][0], qf[t][0], s0);
      s0 = MFMA16(kf[0][1], qf[t][1], s0);
      s1 = MFMA16(kf[1][0], qf[t][0], s1);
      s1 = MFMA16(kf[1][1], qf[t][1], s1);
      union PK { uint2 u2; bf16 h[4]; };
      PK a, b;
      float p0 = EXP2F(s0[0]), p1 = EXP2F(s0[1]), p2 = EXP2F(s0[2]), p3 = EXP2F(s0[3]);
      float p4 = EXP2F(s1[0]), p5 = EXP2F(s1[1]), p6 = EXP2F(s1[2]), p7 = EXP2F(s1[3]);
      l[t] += ((p0 + p1) + (p2 + p3)) + ((p4 + p5) + (p6 + p7));
      a.h[0] = (bf16)p0; a.h[1] = (bf16)p1; a.h[2] = (bf16)p2; a.h[3] = (bf16)p3;
      b.h[0] = (bf16)p4; b.h[1] = (bf16)p5; b.h[2] = (bf16)p6; b.h[3] = (bf16)p7;
      // P[q=c15][key]: keys nt*16+g*4.. ; then read B-frag pf[j]=P[c15][g*8+j]
      *(uint2*)&Pw[c15 * 40 + g * 4] = a.u2;
      *(uint2*)&Pw[c15 * 40 + 16 + g * 4] = b.u2;
      bf16x8 pf = *(const bf16x8*)&Pw[c15 * 40 + g * 8];
#pragma unroll
      for (int nt = 0; nt < 4; ++nt) O[t][nt] = MFMA16(vf[nt], pf, O[t][nt]);
    }
  }
#undef STAGE

  // own-wave l reduction (sum over g-lanes sharing c15)
#pragma unroll
  for (int t = 0; t < 4; ++t) {
    l[t] += __shfl_xor(l[t], 16);
    l[t] += __shfl_xor(l[t], 32);
  }

  // cross-wave merge: ky=1 publishes O,l; ky=0 combines, normalizes, stores.
  __syncthreads();  // all waves done reading staging LDS (redbuf aliases it)
  if (ky == 1) {
#pragma unroll
    for (int t = 0; t < 4; ++t) {
#pragma unroll
      for (int nt = 0; nt < 4; ++nt)
        *(f32x4*)&redbuf[qh * 4352 + (t * 16 + c15) * 68 + nt * 16 + g * 4] = O[t][nt];
      if (g == 0) lred[qh][t][c15] = l[t];
    }
  }
  __syncthreads();
  if (ky == 0) {
    const int bb = bh >> 4, hh = bh & 15;
#pragma unroll
    for (int t = 0; t < 4; ++t) {
      const float inv = 1.0f / (l[t] + lred[qh][t][c15]);
      const size_t base = ((size_t)(bb * S_N + qb + t * 16 + c15) * H_N + hh) * DK;
#pragma unroll
      for (int nt = 0; nt < 4; ++nt) {
        f32x4 o = *(const f32x4*)&redbuf[qh * 4352 + (t * 16 + c15) * 68 + nt * 16 + g * 4];
        bf16x4 v4;
#pragma unroll
        for (int r = 0; r < 4; ++r) v4[r] = (bf16)((O[t][nt][r] + o[r]) * inv);
        *(bf16x4*)&ctx[base + nt * 16 + g * 4] = v4;
      }
    }
  }
}

// ---------------- output projection: out = ctx @ Wo^T (fp32), 64x128 tiles ----------------
__global__ __launch_bounds__(256) void gemm_out(
    const bf16* __restrict__ Cx, const bf16* __restrict__ Wo,
    float* __restrict__ out) {
  __shared__ __align__(16) bf16 As[64 * 32];
  __shared__ __align__(16) bf16 Bs[128 * 32];
  const int tid = threadIdx.x;
  const int wave = tid >> 6, lane = tid & 63;
  const int c15 = lane & 15, g = lane >> 4;
  const int mw = (wave & 1) * 32, nw = (wave >> 1) * 64;
  const int row0 = blockIdx.x * 64;
  const int n0 = blockIdx.y * 128;
  const bf16* Asrc = Cx + (size_t)row0 * DM;
  const bf16* Bsrc = Wo + (size_t)n0 * DM;
  const int giA = wave * 64 + lane;
  const int rA = giA >> 2, cA = (giA & 3) * 8;
  const int giB = wave * 128 + lane;
  const int rB0 = giB >> 2, cB0 = (giB & 3) * 8;
  const int rB1 = (giB + 64) >> 2, cB1 = ((giB + 64) & 3) * 8;

  f32x4 acc[2][4] = {};
  for (int kt = 0; kt < DM / 32; ++kt) {
    const int k0 = kt * 32;
    __syncthreads();
    gl_lds16(Asrc + (size_t)rA * DM + k0 + cA, &As[wave * 512]);
    gl_lds16(Bsrc + (size_t)rB0 * DM + k0 + cB0, &Bs[wave * 1024]);
    gl_lds16(Bsrc + (size_t)rB1 * DM + k0 + cB1, &Bs[wave * 1024 + 512]);
    __syncthreads();
    bf16x8 af[2], bfr[4];
#pragma unroll
    for (int t = 0; t < 2; ++t)
      af[t] = *(const bf16x8*)&As[(mw + t * 16 + c15) * 32 + g * 8];
#pragma unroll
    for (int t = 0; t < 4; ++t)
      bfr[t] = *(const bf16x8*)&Bs[(nw + t * 16 + c15) * 32 + g * 8];
#pragma unroll
    for (int mt = 0; mt < 2; ++mt)
#pragma unroll
      for (int nt = 0; nt < 4; ++nt)
        acc[mt][nt] = MFMA16(af[mt], bfr[nt], acc[mt][nt]);
  }
#pragma unroll
  for (int mt = 0; mt < 2; ++mt)
#pragma unroll
    for (int r = 0; r < 4; ++r) {
      const int row = row0 + mw + mt * 16 + g * 4 + r;
#pragma unroll
      for (int nt = 0; nt < 4; ++nt)
        out[(size_t)row * DM + n0 + nw + nt * 16 + c15] = acc[mt][nt][r];
    }
}

extern "C" void kernel_launch(void* const* d_in, const int* in_sizes, int n_in,
                              void* d_out, int out_size, void* d_ws, size_t ws_size,
                              hipStream_t stream) {
  const float* hs = (const float*)d_in[0];
  const int* pos = (const int*)d_in[1];
  const float* wq = (const float*)d_in[2];
  const float* wk = (const float*)d_in[3];
  const float* wv = (const float*)d_in[4];
  const float* wo = (const float*)d_in[5];
  float* out = (float*)d_out;
  bf16* ws = (bf16*)d_ws;
  float2* tab = (float2*)(ws + OFF_C);  // aliases ctx region; disjoint lifetime

  cast_all<<<8192, 256, 0, stream>>>(hs, wq, wk, wv, wo, ws, tab);

  dim3 gq(M_N / 128, (3 * DM) / 128);
  gemm_qkv_rope<<<gq, 256, 0, stream>>>(ws + OFF_X, ws + OFF_W, pos, tab,
                                        ws + OFF_Q, ws + OFF_K, ws + OFF_V);

  // grid 512: blockIdx = qt*32 + bh (128-query tiles, XCD-local per head)
  flash_attn<<<B_N * H_N * (S_N / 128), 256, 0, stream>>>(
      ws + OFF_Q, ws + OFF_K, ws + OFF_V, ws + OFF_C);

  dim3 go(M_N / 64, DM / 128);
  gemm_out<<<go, 256, 0, stream>>>(ws + OFF_C, ws + OFF_W + 3 * NW, out);
}

// Round 11
// 193.893 us; speedup vs baseline: 1.5886x; 1.5886x over previous
//
#include <hip/hip_runtime.h>
#include <hip/hip_bf16.h>
#include <math.h>

typedef __bf16 bf16;
typedef __bf16 bf16x8 __attribute__((ext_vector_type(8)));
typedef __bf16 bf16x4 __attribute__((ext_vector_type(4)));
typedef float f32x4 __attribute__((ext_vector_type(4)));

#define MFMA16(a, b, c) __builtin_amdgcn_mfma_f32_16x16x32_bf16((a), (b), (c), 0, 0, 0)
#define EXP2F(x) __builtin_amdgcn_exp2f(x)  // v_exp_f32: computes 2^x

// async global->LDS, 16B per lane; LDS dest = (wave-uniform) base + lane*16
__device__ __forceinline__ void gl_lds16(const bf16* g, bf16* l) {
  __builtin_amdgcn_global_load_lds(
      (const __attribute__((address_space(1))) void*)g,
      (__attribute__((address_space(3))) void*)l, 16, 0, 0);
}

// problem dims
static constexpr int B_N = 2, S_N = 2048, DM = 1024, H_N = 16, DK = 64;
static constexpr int M_N = B_N * S_N;             // 4096
static constexpr size_t NX = (size_t)M_N * DM;    // 4M elements
static constexpr size_t NW = (size_t)DM * DM;     // 1M elements
// workspace layout (bf16 elements)
static constexpr size_t OFF_X = 0;
static constexpr size_t OFF_W = NX;               // Wq,Wk,Wv,Wo
static constexpr size_t OFF_Q = OFF_W + 4 * NW;   // Q [b,h,s,d] (pre-scaled by log2e/8, roped)
static constexpr size_t OFF_K = OFF_Q + NX;       // K [b,h,s,d] (roped)
static constexpr size_t OFF_V = OFF_K + NX;       // V^T [b,h,d,s]
static constexpr size_t OFF_C = OFF_V + NX;       // ctx [b,s,h*d]; rope table aliases its head
// total 24M bf16 = 48 MB

// ---------------- fp32 -> bf16 cast + RoPE table (fused) ----------------
__global__ __launch_bounds__(256) void cast_all(
    const float* __restrict__ x, const float* __restrict__ wq,
    const float* __restrict__ wk, const float* __restrict__ wv,
    const float* __restrict__ wo, bf16* __restrict__ dst,
    float2* __restrict__ tab) {
  size_t i = ((size_t)blockIdx.x * 256 + threadIdx.x) * 4;
  const float* src;
  size_t off;
  if (i < NX) {
    src = x; off = i;
  } else {
    size_t e = i - NX;
    int wi = (int)(e >> 20);
    src = (wi == 0) ? wq : (wi == 1) ? wk : (wi == 2) ? wv : wo;
    off = e & (NW - 1);
  }
  float4 v = *(const float4*)(src + off);
  bf16x4 o = {(bf16)v.x, (bf16)v.y, (bf16)v.z, (bf16)v.w};
  *(bf16x4*)(dst + i) = o;
  if (blockIdx.x < 256) {
    int t = blockIdx.x * 256 + threadIdx.x;  // 65536 entries
    int s = t >> 5, j = t & 31;
    float invf = powf(10000.f, -(float)(2 * j) / 64.f);
    float sn, cs;
    sincosf((float)s * invf, &sn, &cs);
    tab[t] = make_float2(cs, sn);
  }
}

// ---------------- QKV GEMM (M=4096,N=3072,K=1024) + fused RoPE, V written transposed ----------------
__global__ __launch_bounds__(256) void gemm_qkv_rope(
    const bf16* __restrict__ X, const bf16* __restrict__ W3,
    const int* __restrict__ pos_ids, const float2* __restrict__ tab,
    bf16* __restrict__ Qo, bf16* __restrict__ Ko, bf16* __restrict__ Vt) {
  __shared__ __align__(16) bf16 As[128 * 32];
  __shared__ __align__(16) bf16 Bs[128 * 32];
  const int tid = threadIdx.x;
  const int wave = tid >> 6, lane = tid & 63;
  const int c15 = lane & 15, g = lane >> 4;
  const int mw = (wave & 1) * 64, nw = (wave >> 1) * 64;
  const int row0 = blockIdx.x * 128;
  const int n0 = blockIdx.y * 128;
  const bf16* Asrc = X + (size_t)row0 * DM;
  const bf16* Bsrc = W3 + (size_t)n0 * DM;
  const int srA = wave * 32 + (lane >> 2);
  const int cph = lane & 3;

  f32x4 acc[4][4] = {};
  for (int kt = 0; kt < DM / 32; ++kt) {
    const int k0 = kt * 32;
    __syncthreads();
#pragma unroll
    for (int c = 0; c < 2; ++c) {
      const int r = srA + c * 16;
      gl_lds16(Asrc + (size_t)r * DM + k0 + cph * 8, &As[wave * 1024 + c * 512]);
      gl_lds16(Bsrc + (size_t)r * DM + k0 + cph * 8, &Bs[wave * 1024 + c * 512]);
    }
    __syncthreads();
    bf16x8 af[4], bfr[4];
#pragma unroll
    for (int t = 0; t < 4; ++t)
      af[t] = *(const bf16x8*)&As[(mw + t * 16 + c15) * 32 + g * 8];
#pragma unroll
    for (int t = 0; t < 4; ++t)
      bfr[t] = *(const bf16x8*)&Bs[(nw + t * 16 + c15) * 32 + g * 8];
#pragma unroll
    for (int mt = 0; mt < 4; ++mt)
#pragma unroll
      for (int nt = 0; nt < 4; ++nt)
        acc[mt][nt] = MFMA16(af[mt], bfr[nt], acc[mt][nt]);
  }

  // epilogue: C/D col = nt*16+c15, row = g*4+r
  const int Wsel = n0 >> 10;             // 0=q, 1=k, 2=v
  const int colbase = (n0 & 1023) + nw;  // multiple of 64 -> one head
  const int h = colbase >> 6;
  if (Wsel == 2) {
#pragma unroll
    for (int mt = 0; mt < 4; ++mt) {
      const int srow = row0 + mw + mt * 16 + g * 4;
      const int bb = srow >> 11, ss = srow & 2047;
      const size_t vb = ((size_t)(bb * H_N + h) * DK) * S_N + ss;
#pragma unroll
      for (int nt = 0; nt < 4; ++nt) {
        bf16x4 v4;
#pragma unroll
        for (int r = 0; r < 4; ++r) v4[r] = (bf16)acc[mt][nt][r];
        *(bf16x4*)&Vt[vb + (size_t)(nt * 16 + c15) * S_N] = v4;
      }
    }
  } else {
    bf16* dst = (Wsel == 0) ? Qo : Ko;
    // Q pre-scale folds 1/sqrt(64) AND log2(e) so flash can use exp2 directly.
    const float sc = (Wsel == 0) ? 0.125f * 1.44269504088896f : 1.0f;
#pragma unroll
    for (int mt = 0; mt < 4; ++mt) {
#pragma unroll
      for (int r = 0; r < 4; ++r) {
        const int row = row0 + mw + mt * 16 + g * 4 + r;
        const int bb = row >> 11, ss = row & 2047;
        const int pos = pos_ids[row];
        const float2 c0 = tab[pos * 32 + c15];       // freq j = c15
        const float2 c1 = tab[pos * 32 + 16 + c15];  // freq j = 16+c15
        const size_t base = ((size_t)(bb * H_N + h) * S_N + ss) * DK;
#pragma unroll
        for (int ntp = 0; ntp < 2; ++ntp) {
          float x1 = acc[mt][ntp][r], x2 = acc[mt][ntp + 2][r];
          float cs = ntp ? c1.x : c0.x, sn = ntp ? c1.y : c0.y;
          dst[base + ntp * 16 + c15] = (bf16)((x1 * cs - x2 * sn) * sc);
          dst[base + ntp * 16 + c15 + 32] = (bf16)((x2 * cs + x1 * sn) * sc);
        }
      }
    }
  }
}

// ---------------- flash attention: split-key waves, SHARED staging ----------------
// 128 q/block, 4 waves = (qh: 64-q half) x (ky: 32-key slice). K/V tiles shared per
// ky-pair: qh=0 wave stages K, qh=1 stages V. One __syncthreads per iter + dbuf.
// O,l additive over ky -> one merge. LDS 38.4 KB -> 4 blocks/CU; bounds (256,2)
// leaves the allocator free (R10's (256,4) forced 64 VGPRs -> 342 MB scratch spill).
__global__ __launch_bounds__(256, 2) void flash_attn(
    const bf16* __restrict__ Q, const bf16* __restrict__ K,
    const bf16* __restrict__ Vt, bf16* __restrict__ ctx) {
  // carve one contiguous block: K[ky][buf] | V[ky][buf] | P[wave]  (elements)
  //   K: [0, 8192)   slice(ky,buf) at (ky*2+buf)*2048
  //   V: [8192, 16384)
  //   P: [16384, 18944)  wave*640, rows 16 stride 40
  __shared__ __align__(16) bf16 smem[18944];
  __shared__ float lred[2][4][16];
  float* redbuf = (float*)smem;  // merge scratch: 2 qh x 64 rows x stride 68 floats

  const int tid = threadIdx.x;
  const int wave = tid >> 6, lane = tid & 63;
  const int c15 = lane & 15, g = lane >> 4;
  const int qh = wave >> 1, ky = wave & 1;
  const int bh = blockIdx.x & 31;   // b*16+h (XCD = bh%8)
  const int qt = blockIdx.x >> 5;   // 128-query tile, 0..15
  const size_t hb = (size_t)bh * S_N * DK;
  const bf16* Qb = Q + hb;
  const bf16* Kb = K + hb;
  const bf16* Vb = Vt + hb;  // [d][s] rows, stride S_N
  bf16* Pw = &smem[16384 + wave * 640];

  // Q B-frags: 4 q-tiles of 16 for this wave's 64-query half
  const int qb = qt * 128 + qh * 64;
  bf16x8 qf[4][2];
#pragma unroll
  for (int t = 0; t < 4; ++t) {
    qf[t][0] = *(const bf16x8*)&Qb[(size_t)(qb + t * 16 + c15) * DK + g * 8];
    qf[t][1] = *(const bf16x8*)&Qb[(size_t)(qb + t * 16 + c15) * DK + 32 + g * 8];
  }

  f32x4 O[4][4] = {};  // [q-tile][d-tile]: O^T row d = nt*16+g*4+r, col q = c15
  float l[4] = {0.f, 0.f, 0.f, 0.f};
  const int sw = c15 & 7;
  const int vslot = (g + (c15 >> 1)) & 3;  // V read-granule swizzle

  constexpr int NTK = S_N / 64;  // 32 iters; each wave sees its ky 32-key slice
#define STAGE(kt_, b_)                                                            \
  if (qh == 0) { /* stage K slice ky */                                           \
    const bf16* Ksrc = Kb + (size_t)((kt_)*64 + ky * 32) * DK;                    \
    _Pragma("unroll") for (int c = 0; c < 4; ++c) {                               \
      const int gi = c * 64 + lane;                                               \
      const int rr = gi >> 3, cp = gi & 7;                                        \
      const int cd = cp ^ (rr & 7);                                               \
      gl_lds16(Ksrc + (size_t)rr * 64 + cd * 8, &smem[(ky * 2 + (b_)) * 2048 + c * 512]); \
    }                                                                             \
  } else { /* stage V slice ky */                                                 \
    const bf16* Vsrc = Vb + (kt_)*64 + ky * 32;                                   \
    _Pragma("unroll") for (int c = 0; c < 4; ++c) {                               \
      const int gi = c * 64 + lane;                                               \
      const int rv = gi >> 2, cpv = gi & 3;                                       \
      const int cdv = (cpv - ((rv & 15) >> 1)) & 3;                               \
      gl_lds16(Vsrc + (size_t)rv * S_N + cdv * 8, &smem[8192 + (ky * 2 + (b_)) * 2048 + c * 512]); \
    }                                                                             \
  }

  STAGE(0, 0)
  for (int kt = 0; kt < NTK; ++kt) {
    __syncthreads();  // tile kt resident (its loads were issued one full phase ago)
    if (kt + 1 < NTK) STAGE(kt + 1, (kt + 1) & 1)
    const bf16* Kl = &smem[(ky * 2 + (kt & 1)) * 2048];
    const bf16* Vl = &smem[8192 + (ky * 2 + (kt & 1)) * 2048];

    // K A-frags: 2 key-subtiles x 2 d-halves (granule-XOR swizzle, round-trips cd)
    bf16x8 kf[2][2];
#pragma unroll
    for (int nt = 0; nt < 2; ++nt) {
      const int krow = (nt * 16 + c15) * 64;
      kf[nt][0] = *(const bf16x8*)&Kl[krow + ((g ^ sw) * 8)];
      kf[nt][1] = *(const bf16x8*)&Kl[krow + (((4 | g) ^ sw) * 8)];
    }
    // V A-frags: 4 d-subtiles, k = 32 keys (slot swizzle: data granule g at vslot)
    bf16x8 vf[4];
#pragma unroll
    for (int nt = 0; nt < 4; ++nt)
      vf[nt] = *(const bf16x8*)&Vl[(nt * 16 + c15) * 32 + vslot * 8];

    // per q-tile: S^T = K·Q^T (32 keys x 16 q) -> exp2 -> P LDS -> PV
#pragma unroll
    for (int t = 0; t < 4; ++t) {
      f32x4 s0 = {}, s1 = {};
      s0 = MFMA16(kf[0][0], qf[t][0], s0);
      s0 = MFMA16(kf[0][1], qf[t][1], s0);
      s1 = MFMA16(kf[1][0], qf[t][0], s1);
      s1 = MFMA16(kf[1][1], qf[t][1], s1);
      union PK { uint2 u2; bf16 h[4]; };
      PK a, b;
      float p0 = EXP2F(s0[0]), p1 = EXP2F(s0[1]), p2 = EXP2F(s0[2]), p3 = EXP2F(s0[3]);
      float p4 = EXP2F(s1[0]), p5 = EXP2F(s1[1]), p6 = EXP2F(s1[2]), p7 = EXP2F(s1[3]);
      l[t] += ((p0 + p1) + (p2 + p3)) + ((p4 + p5) + (p6 + p7));
      a.h[0] = (bf16)p0; a.h[1] = (bf16)p1; a.h[2] = (bf16)p2; a.h[3] = (bf16)p3;
      b.h[0] = (bf16)p4; b.h[1] = (bf16)p5; b.h[2] = (bf16)p6; b.h[3] = (bf16)p7;
      // P[q=c15][key]: keys nt*16+g*4.. ; then read B-frag pf[j]=P[c15][g*8+j]
      *(uint2*)&Pw[c15 * 40 + g * 4] = a.u2;
      *(uint2*)&Pw[c15 * 40 + 16 + g * 4] = b.u2;
      bf16x8 pf = *(const bf16x8*)&Pw[c15 * 40 + g * 8];
#pragma unroll
      for (int nt = 0; nt < 4; ++nt) O[t][nt] = MFMA16(vf[nt], pf, O[t][nt]);
    }
  }
#undef STAGE

  // own-wave l reduction (sum over g-lanes sharing c15)
#pragma unroll
  for (int t = 0; t < 4; ++t) {
    l[t] += __shfl_xor(l[t], 16);
    l[t] += __shfl_xor(l[t], 32);
  }

  // cross-wave merge: ky=1 publishes O,l; ky=0 combines, normalizes, stores.
  __syncthreads();  // all waves done reading staging LDS (redbuf aliases it)
  if (ky == 1) {
#pragma unroll
    for (int t = 0; t < 4; ++t) {
#pragma unroll
      for (int nt = 0; nt < 4; ++nt)
        *(f32x4*)&redbuf[qh * 4352 + (t * 16 + c15) * 68 + nt * 16 + g * 4] = O[t][nt];
      if (g == 0) lred[qh][t][c15] = l[t];
    }
  }
  __syncthreads();
  if (ky == 0) {
    const int bb = bh >> 4, hh = bh & 15;
#pragma unroll
    for (int t = 0; t < 4; ++t) {
      const float inv = 1.0f / (l[t] + lred[qh][t][c15]);
      const size_t base = ((size_t)(bb * S_N + qb + t * 16 + c15) * H_N + hh) * DK;
#pragma unroll
      for (int nt = 0; nt < 4; ++nt) {
        f32x4 o = *(const f32x4*)&redbuf[qh * 4352 + (t * 16 + c15) * 68 + nt * 16 + g * 4];
        bf16x4 v4;
#pragma unroll
        for (int r = 0; r < 4; ++r) v4[r] = (bf16)((O[t][nt][r] + o[r]) * inv);
        *(bf16x4*)&ctx[base + nt * 16 + g * 4] = v4;
      }
    }
  }
}

// ---------------- output projection: out = ctx @ Wo^T (fp32), 64x128 tiles ----------------
__global__ __launch_bounds__(256) void gemm_out(
    const bf16* __restrict__ Cx, const bf16* __restrict__ Wo,
    float* __restrict__ out) {
  __shared__ __align__(16) bf16 As[64 * 32];
  __shared__ __align__(16) bf16 Bs[128 * 32];
  const int tid = threadIdx.x;
  const int wave = tid >> 6, lane = tid & 63;
  const int c15 = lane & 15, g = lane >> 4;
  const int mw = (wave & 1) * 32, nw = (wave >> 1) * 64;
  const int row0 = blockIdx.x * 64;
  const int n0 = blockIdx.y * 128;
  const bf16* Asrc = Cx + (size_t)row0 * DM;
  const bf16* Bsrc = Wo + (size_t)n0 * DM;
  const int giA = wave * 64 + lane;
  const int rA = giA >> 2, cA = (giA & 3) * 8;
  const int giB = wave * 128 + lane;
  const int rB0 = giB >> 2, cB0 = (giB & 3) * 8;
  const int rB1 = (giB + 64) >> 2, cB1 = ((giB + 64) & 3) * 8;

  f32x4 acc[2][4] = {};
  for (int kt = 0; kt < DM / 32; ++kt) {
    const int k0 = kt * 32;
    __syncthreads();
    gl_lds16(Asrc + (size_t)rA * DM + k0 + cA, &As[wave * 512]);
    gl_lds16(Bsrc + (size_t)rB0 * DM + k0 + cB0, &Bs[wave * 1024]);
    gl_lds16(Bsrc + (size_t)rB1 * DM + k0 + cB1, &Bs[wave * 1024 + 512]);
    __syncthreads();
    bf16x8 af[2], bfr[4];
#pragma unroll
    for (int t = 0; t < 2; ++t)
      af[t] = *(const bf16x8*)&As[(mw + t * 16 + c15) * 32 + g * 8];
#pragma unroll
    for (int t = 0; t < 4; ++t)
      bfr[t] = *(const bf16x8*)&Bs[(nw + t * 16 + c15) * 32 + g * 8];
#pragma unroll
    for (int mt = 0; mt < 2; ++mt)
#pragma unroll
      for (int nt = 0; nt < 4; ++nt)
        acc[mt][nt] = MFMA16(af[mt], bfr[nt], acc[mt][nt]);
  }
#pragma unroll
  for (int mt = 0; mt < 2; ++mt)
#pragma unroll
    for (int r = 0; r < 4; ++r) {
      const int row = row0 + mw + mt * 16 + g * 4 + r;
#pragma unroll
      for (int nt = 0; nt < 4; ++nt)
        out[(size_t)row * DM + n0 + nw + nt * 16 + c15] = acc[mt][nt][r];
    }
}

extern "C" void kernel_launch(void* const* d_in, const int* in_sizes, int n_in,
                              void* d_out, int out_size, void* d_ws, size_t ws_size,
                              hipStream_t stream) {
  const float* hs = (const float*)d_in[0];
  const int* pos = (const int*)d_in[1];
  const float* wq = (const float*)d_in[2];
  const float* wk = (const float*)d_in[3];
  const float* wv = (const float*)d_in[4];
  const float* wo = (const float*)d_in[5];
  float* out = (float*)d_out;
  bf16* ws = (bf16*)d_ws;
  float2* tab = (float2*)(ws + OFF_C);  // aliases ctx region; disjoint lifetime

  cast_all<<<8192, 256, 0, stream>>>(hs, wq, wk, wv, wo, ws, tab);

  dim3 gq(M_N / 128, (3 * DM) / 128);
  gemm_qkv_rope<<<gq, 256, 0, stream>>>(ws + OFF_X, ws + OFF_W, pos, tab,
                                        ws + OFF_Q, ws + OFF_K, ws + OFF_V);

  // grid 512: blockIdx = qt*32 + bh (128-query tiles, XCD-local per head)
  flash_attn<<<B_N * H_N * (S_N / 128), 256, 0, stream>>>(
      ws + OFF_Q, ws + OFF_K, ws + OFF_V, ws + OFF_C);

  dim3 go(M_N / 64, DM / 128);
  gemm_out<<<go, 256, 0, stream>>>(ws + OFF_C, ws + OFF_W + 3 * NW, out);
}